// Round 8
// baseline (497.074 us; speedup 1.0000x reference)
//
#include <hip/hip_runtime.h>
#include <hip/hip_bf16.h>
#include <math.h>

#define C_CLS   1024
#define NPROXY  8
#define ALLNUM  8192
#define DIM     512
#define TOPK    410
#define LAM     0.3f
#define BATCH   2048
#define LIST_CAP 1024

typedef __bf16 bf16x8 __attribute__((ext_vector_type(8)));
typedef float floatx4 __attribute__((ext_vector_type(4)));
typedef unsigned short ushort_t;

// ws layout (float offsets)
#define WS_RNORM 0                      // 8192
#define WS_SIG   8192                   // 2048 input row norms
#define WS_LP    10240                  // 2048 loss partials
#define WS_RP    12288                  // 2048 reg partials
#define WS_CNT   14336                  // 2048 list counters (u32)
#define WS_ABF   16384                  // 2048*512 bf16
#define WS_PBF   540672                 // 8192*512 bf16
#define WS_STBF  2637824                // 1024*512 bf16
#define WS_LIST  2899968                // 2048*1024 uint2 = 4194304 float-slots
#define WS_SIMBF 7094272                // 2048*8192 bf16 = 8388608 float-slots
                                        // (logits bf16 alias this after rowloss)

// ---------------- helpers ----------------------------------------------------
__device__ inline float block_reduce(float v, int is_max, float* red, int t) {
    #pragma unroll
    for (int o = 32; o > 0; o >>= 1) {
        float w = __shfl_down(v, o);
        v = is_max ? fmaxf(v, w) : (v + w);
    }
    __syncthreads();
    if ((t & 63) == 0) red[t >> 6] = v;
    __syncthreads();
    return is_max ? fmaxf(fmaxf(red[0], red[1]), fmaxf(red[2], red[3]))
                  : (red[0] + red[1] + red[2] + red[3]);
}

__device__ inline ushort_t f2bf(float f) {   // RNE float->bf16
    unsigned u = __float_as_uint(f);
    return (ushort_t)((u + 0x7FFFu + ((u >> 16) & 1u)) >> 16);
}

__device__ inline void ld_g2l_16(const void* g, void* l) {
    __builtin_amdgcn_global_load_lds(
        (const __attribute__((address_space(1))) unsigned int*)g,
        (__attribute__((address_space(3))) unsigned int*)l,
        16, 0, 0);
}

__device__ inline unsigned f2ord(float f) {  // monotone float->uint
    unsigned u = __float_as_uint(f);
    return (u & 0x80000000u) ? ~u : (u | 0x80000000u);
}

// ---------------- K1: fused prep (colnorm+cnt0 | convA+rowsig | tconv P) -----
__global__ __launch_bounds__(256) void k_prep1(const float* __restrict__ P,
                                               const float* __restrict__ input,
                                               float* __restrict__ rnorm,
                                               float* __restrict__ rowsig,
                                               unsigned* __restrict__ cnt,
                                               ushort_t* __restrict__ Abf,
                                               ushort_t* __restrict__ Pbf) {
    __shared__ float tile[32][33];
    __shared__ float red[4];
    int bx = blockIdx.x, t = threadIdx.x;
    if (bx < 32) {
        int j = bx * 256 + t;
        float s = 0.f;
        #pragma unroll 8
        for (int d = 0; d < DIM; ++d) {
            float v = P[(size_t)d * ALLNUM + j];
            s += v * v;
        }
        rnorm[j] = 1.0f / fmaxf(sqrtf(s), 1e-12f);
        if (j < BATCH) cnt[j] = 0u;
    } else if (bx < 32 + 1024) {
        // convA: input fp32 -> bf16 + row norms (block covers exactly 2 rows)
        int a = bx - 32;
        int idx = a * 256 + t;
        float4 v = ((const float4*)input)[idx];
        ushort4 o;
        o.x = f2bf(v.x); o.y = f2bf(v.y); o.z = f2bf(v.z); o.w = f2bf(v.w);
        ((ushort4*)Abf)[idx] = o;
        float sq = v.x * v.x + v.y * v.y + v.z * v.z + v.w * v.w;
        #pragma unroll
        for (int off = 32; off > 0; off >>= 1) sq += __shfl_down(sq, off);
        int lane = t & 63, w = t >> 6;
        if (lane == 0) red[w] = sq;
        __syncthreads();
        if (t == 0) {
            rowsig[2 * a]     = sqrtf(red[0] + red[1]);
            rowsig[2 * a + 1] = sqrtf(red[2] + red[3]);
        }
    } else {
        int id = bx - 1056;
        int c0 = (id & 255) * 32, r0 = (id >> 8) * 32;
        int tc = t & 31, tr = t >> 5;
        #pragma unroll
        for (int p = 0; p < 4; ++p)
            tile[tr + p * 8][tc] = P[(size_t)(r0 + tr + p * 8) * ALLNUM + c0 + tc];
        __syncthreads();
        #pragma unroll
        for (int p = 0; p < 4; ++p) {
            int oc = tr + p * 8;
            Pbf[(size_t)(c0 + oc) * DIM + r0 + tc] = f2bf(tile[tc][oc]);
        }
    }
}

// ---------------- K2: S^T bf16 direct: St[c][d] = sum_n P[d][8c+n]*rn[8c+n] --
__global__ __launch_bounds__(256) void k_prep2(const float* __restrict__ P,
                                               const float* __restrict__ rnorm,
                                               ushort_t* __restrict__ Stbf) {
    __shared__ float tile[32][33];       // [d_local][c_local]
    int bx = blockIdx.x, t = threadIdx.x;
    int c0 = (bx & 31) * 32, d0 = (bx >> 5) * 32;
    int cl = t & 31, dl8 = t >> 5;
    #pragma unroll
    for (int p = 0; p < 4; ++p) {
        int d = d0 + dl8 + 8 * p;
        int c = c0 + cl;
        const float* pp = P + (size_t)d * ALLNUM + c * NPROXY;
        const float* rn = rnorm + c * NPROXY;
        float4 a = *(const float4*)pp;
        float4 b = *(const float4*)(pp + 4);
        float4 ra = *(const float4*)rn;
        float4 rb = *(const float4*)(rn + 4);
        tile[dl8 + 8 * p][cl] = a.x * ra.x + a.y * ra.y + a.z * ra.z + a.w * ra.w +
                                b.x * rb.x + b.y * rb.y + b.z * rb.z + b.w * rb.w;
    }
    __syncthreads();
    #pragma unroll
    for (int p = 0; p < 4; ++p) {
        int cl2 = dl8 + 8 * p, dl2 = t & 31;
        Stbf[(size_t)(c0 + cl2) * DIM + d0 + dl2] = f2bf(tile[dl2][cl2]);
    }
}

// ---------------- MFMA GEMM: C[M][N] = A[M][512] * B[N][512]^T (bf16 out) ----
// MODE 0 (sim): scale rnorm[col]; ALSO append elements >= loT(row) to per-row
//               candidate list (fused top-k classification).
// MODE 1 (logits): scale rnorm[row].
template<int MODE>
__global__ __launch_bounds__(256) void k_gemm_bt(const ushort_t* __restrict__ A,
                                                 const ushort_t* __restrict__ B,
                                                 const float* __restrict__ rnorm,
                                                 const float* __restrict__ rowsig,
                                                 unsigned* __restrict__ cnt,
                                                 uint2* __restrict__ list,
                                                 ushort_t* __restrict__ Cmat, int Ndim) {
    __shared__ __align__(16) ushort_t sA[128 * 64];
    __shared__ __align__(16) ushort_t sB[128 * 64];
    int t = threadIdx.x;
    int w = t >> 6, lane = t & 63;
    int wm = w >> 1, wn = w & 1;
    int bi = blockIdx.y * 128, bj = blockIdx.x * 128;

    floatx4 acc[4][4];
    #pragma unroll
    for (int tm = 0; tm < 4; ++tm)
        #pragma unroll
        for (int tn = 0; tn < 4; ++tn)
            acc[tm][tn] = (floatx4){0.f, 0.f, 0.f, 0.f};

    for (int k0 = 0; k0 < DIM; k0 += 64) {
        #pragma unroll
        for (int it = 0; it < 4; ++it) {
            int c = w * 256 + it * 64 + lane;
            int m = c >> 3, s = c & 7;
            int q = s ^ (m & 7);
            ld_g2l_16(A + ((size_t)(bi + m) << 9) + k0 + q * 8,
                      &sA[(w * 256 + it * 64) * 8]);
        }
        #pragma unroll
        for (int it = 0; it < 4; ++it) {
            int c = w * 256 + it * 64 + lane;
            int m = c >> 3, s = c & 7;
            int q = s ^ (m & 7);
            ld_g2l_16(B + ((size_t)(bj + m) << 9) + k0 + q * 8,
                      &sB[(w * 256 + it * 64) * 8]);
        }
        asm volatile("s_waitcnt vmcnt(0)" ::: "memory");
        __syncthreads();

        #pragma unroll
        for (int kk = 0; kk < 2; ++kk) {
            bf16x8 af[4], bfr[4];
            int ml = lane & 15, q = lane >> 4;
            #pragma unroll
            for (int tm = 0; tm < 4; ++tm) {
                int m = wm * 64 + tm * 16 + ml;
                int s = (kk * 4 + q) ^ (m & 7);
                af[tm] = *(const bf16x8*)&sA[m * 64 + s * 8];
            }
            #pragma unroll
            for (int tn = 0; tn < 4; ++tn) {
                int n = wn * 64 + tn * 16 + ml;
                int s = (kk * 4 + q) ^ (n & 7);
                bfr[tn] = *(const bf16x8*)&sB[n * 64 + s * 8];
            }
            #pragma unroll
            for (int tm = 0; tm < 4; ++tm)
                #pragma unroll
                for (int tn = 0; tn < 4; ++tn)
                    acc[tm][tn] = __builtin_amdgcn_mfma_f32_16x16x32_bf16(
                        af[tm], bfr[tn], acc[tm][tn], 0, 0, 0);
        }
        __syncthreads();
    }

    int ml = lane & 15, qd = lane >> 4;
    #pragma unroll
    for (int tm = 0; tm < 4; ++tm) {
        int rowb = bi + wm * 64 + tm * 16 + qd * 4;
        #pragma unroll
        for (int i = 0; i < 4; ++i) {
            int row = rowb + i;
            float lo = 0.f, rscale = 0.f;
            if (MODE == 0) lo = rowsig[row] * (1.47f / 22.616f);
            else           rscale = rnorm[row];
            #pragma unroll
            for (int tn = 0; tn < 4; ++tn) {
                int col = bj + wn * 64 + tn * 16 + ml;
                float v = acc[tm][tn][i] * (MODE == 0 ? rnorm[col] : rscale);
                Cmat[(size_t)row * Ndim + col] = f2bf(v);
                if (MODE == 0 && v >= lo) {
                    unsigned slot = atomicAdd(&cnt[row], 1u);
                    if (slot < LIST_CAP)
                        list[(size_t)row * LIST_CAP + slot] =
                            make_uint2(__float_as_uint(v), (unsigned)col);
                }
            }
        }
    }
}

// ---------------- K4: per-row topk from candidate list + class sums + loss ---
// List holds all elements >= loT = 1.47 sig (f32 values from gemm registers).
// Definite (>= 1.80 sig, non-target) -> class bins; band -> rank-select the
// remaining rank; 8 target proxies always selected (sum read from bf16 sim).
// Exact fallback: binary search on the bf16 sim row (never taken: cap +19sd).
__global__ __launch_bounds__(256) void k_rowloss(const uint2* __restrict__ list,
                                                 const unsigned* __restrict__ cnt,
                                                 const ushort_t* __restrict__ simbf,
                                                 const int* __restrict__ target,
                                                 const float* __restrict__ rowsig,
                                                 float* __restrict__ loss_part) {
    __shared__ float    s_cls[C_CLS];        // 4 KB
    __shared__ float    s_bval[LIST_CAP];    // 4 KB band values
    __shared__ ushort_t s_bcol[LIST_CAP];    // 2 KB band cols
    __shared__ unsigned sh_bc;
    __shared__ float    sh_thr;
    __shared__ int      sh_fb;
    __shared__ float    red[4];

    int b = blockIdx.x, t = threadIdx.x;
    int tgt = target[b];
    float sig = rowsig[b] * (1.0f / 22.616f);
    float hiT = 1.80f * sig;
    unsigned n = cnt[b];
    int fb_pre = (n > LIST_CAP) ? 1 : 0;

    if (t == 0) sh_bc = 0;
    #pragma unroll
    for (int i = 0; i < 4; ++i) s_cls[t + 256 * i] = 0.f;
    __syncthreads();

    float ndef = 0.f;
    if (!fb_pre) {
        const uint2* L = list + (size_t)b * LIST_CAP;
        for (int i = t; i < (int)n; i += 256) {
            uint2 e = L[i];
            float v = __uint_as_float(e.x);
            int col = (int)e.y;
            int cls = col >> 3;
            if (cls != tgt) {
                if (v >= hiT) {
                    ndef += 1.f;
                    atomicAdd(&s_cls[cls], v);
                } else {
                    unsigned k2 = atomicAdd(&sh_bc, 1u);
                    s_bval[k2] = v; s_bcol[k2] = (ushort_t)col;
                }
            }
        }
        if (t == 0) {   // target class: sum of its 8 proxies (always selected)
            uint4 tv = *(const uint4*)(simbf + (size_t)b * ALLNUM + 8 * tgt);
            const unsigned* u = (const unsigned*)&tv;
            float s = 0.f;
            #pragma unroll
            for (int k = 0; k < 4; ++k) {
                s += __uint_as_float(u[k] << 16);
                s += __uint_as_float(u[k] & 0xFFFF0000u);
            }
            s_cls[tgt] = s;
        }
    }
    float ndefT = block_reduce(ndef, 0, red, t);
    int bc = (int)sh_bc;
    int kq = (TOPK - NPROXY) - (int)ndefT;
    if (t == 0) sh_fb = (fb_pre || kq < 0 || bc < kq) ? 1 : 0;
    __syncthreads();

    if (!sh_fb) {
        if (kq > 0) {
            // rank-select kq-th largest among bc band entries
            for (int j = t; j < bc; j += 256) {
                float vj = s_bval[j];
                unsigned g = 0, geq = 0;
                for (int i = 0; i < bc; ++i) {
                    float vi = s_bval[i];
                    g   += (vi > vj) ? 1u : 0u;
                    geq += (vi >= vj) ? 1u : 0u;
                }
                if (g < (unsigned)kq && geq >= (unsigned)kq) sh_thr = vj;
            }
            __syncthreads();
            float thr = sh_thr;
            for (int j = t; j < bc; j += 256)
                if (s_bval[j] >= thr)
                    atomicAdd(&s_cls[s_bcol[j] >> 3], s_bval[j]);
        }
    } else {
        // exact fallback from bf16 sim row (never taken for this input)
        __syncthreads();
        #pragma unroll
        for (int i = 0; i < 4; ++i) s_cls[t + 256 * i] = 0.f;
        __syncthreads();
        const ushort_t* rowp = simbf + (size_t)b * ALLNUM;
        uint4 r4[4];
        float fv[32];
        #pragma unroll
        for (int c = 0; c < 4; ++c) r4[c] = ((const uint4*)rowp)[t + 256 * c];
        #pragma unroll
        for (int c = 0; c < 4; ++c) {
            const unsigned* u = (const unsigned*)&r4[c];
            #pragma unroll
            for (int k = 0; k < 4; ++k) {
                fv[c * 8 + 2 * k]     = __uint_as_float(u[k] << 16);
                fv[c * 8 + 2 * k + 1] = __uint_as_float(u[k] & 0xFFFF0000u);
            }
        }
        // chunk c of thread t covers exactly class (t + 256c)
        #pragma unroll
        for (int c = 0; c < 4; ++c) {
            int cls = t + 256 * c;
            if (cls == tgt) {
                float s = 0.f;
                #pragma unroll
                for (int e = 0; e < 8; ++e) s += fv[c * 8 + e];
                s_cls[tgt] = s;
            }
        }
        unsigned L2 = 0u, R2 = 0xFFFFFFFFu;
        while (R2 - L2 > 1) {
            unsigned mid = L2 + ((R2 - L2) >> 1);
            float cg = 0.f;
            #pragma unroll
            for (int c = 0; c < 4; ++c) {
                int cls = t + 256 * c;
                if (cls != tgt) {
                    #pragma unroll
                    for (int e = 0; e < 8; ++e)
                        cg += (f2ord(fv[c * 8 + e]) >= mid) ? 1.f : 0.f;
                }
            }
            cg = block_reduce(cg, 0, red, t);
            if (cg >= (float)(TOPK - NPROXY)) L2 = mid; else R2 = mid;
            __syncthreads();
        }
        #pragma unroll
        for (int c = 0; c < 4; ++c) {
            int cls = t + 256 * c;
            if (cls != tgt) {
                float s = 0.f;
                #pragma unroll
                for (int e = 0; e < 8; ++e) {
                    float v = fv[c * 8 + e];
                    if (f2ord(v) >= L2) s += v;
                }
                s_cls[cls] = s;    // sole writer for this class
            }
        }
    }
    __syncthreads();

    // masked (logit != 0) stable softmax loss — one float4 per thread
    float4 cv = ((const float4*)s_cls)[t];
    float m = -1e30f;
    if (cv.x != 0.0f) m = fmaxf(m, cv.x);
    if (cv.y != 0.0f) m = fmaxf(m, cv.y);
    if (cv.z != 0.0f) m = fmaxf(m, cv.z);
    if (cv.w != 0.0f) m = fmaxf(m, cv.w);
    m = block_reduce(m, 1, red, t);
    float se = 0.f;
    if (cv.x != 0.0f) se += expf(cv.x - m);
    if (cv.y != 0.0f) se += expf(cv.y - m);
    if (cv.z != 0.0f) se += expf(cv.z - m);
    if (cv.w != 0.0f) se += expf(cv.w - m);
    se = block_reduce(se, 0, red, t);
    if (t == 0) {
        float lt = s_cls[tgt];
        float predict_t = expf(lt - m) / (1e-8f * expf(-m) + se);
        loss_part[b] = -logf(predict_t + 1e-20f);
    }
}

// ---------------- K5: reg logsumexp - diag, one wave per row (bf16 in) -------
__global__ __launch_bounds__(256) void k_regloss(const ushort_t* __restrict__ logits,
                                                 float* __restrict__ reg_part) {
    __shared__ float bsum[4];
    int t = threadIdx.x, lane = t & 63, wid = t >> 6;
    int i = blockIdx.x * 4 + wid;
    const ushort_t* row = logits + (size_t)i * C_CLS;
    uint4 c0 = ((const uint4*)row)[lane];
    uint4 c1 = ((const uint4*)(row + 512))[lane];

    float f[16];
    const unsigned* u0 = (const unsigned*)&c0;
    const unsigned* u1 = (const unsigned*)&c1;
    #pragma unroll
    for (int k = 0; k < 4; ++k) {
        f[2 * k]     = __uint_as_float(u0[k] << 16);
        f[2 * k + 1] = __uint_as_float(u0[k] & 0xFFFF0000u);
        f[8 + 2 * k]     = __uint_as_float(u1[k] << 16);
        f[8 + 2 * k + 1] = __uint_as_float(u1[k] & 0xFFFF0000u);
    }

    int cstar = i >> 3;
    int chunk = cstar >> 9, within = cstar & 511;
    float sd = 0.f;
    if (lane == (within >> 3)) sd = f[chunk * 8 + (within & 7)];

    float m = -1e30f;
    #pragma unroll
    for (int k = 0; k < 16; ++k) m = fmaxf(m, f[k]);
    #pragma unroll
    for (int off = 32; off > 0; off >>= 1) m = fmaxf(m, __shfl_xor(m, off));

    float se = 0.f;
    #pragma unroll
    for (int k = 0; k < 16; ++k) se += expf(f[k] - m);
    #pragma unroll
    for (int off = 32; off > 0; off >>= 1) se += __shfl_xor(se, off);
    #pragma unroll
    for (int off = 32; off > 0; off >>= 1) sd += __shfl_xor(sd, off);

    if (lane == 0) bsum[wid] = m + logf(se) - sd;
    __syncthreads();
    if (t == 0)
        reg_part[blockIdx.x] = bsum[0] + bsum[1] + bsum[2] + bsum[3];
}

// ---------------- K6: finalize (reduce 2048+2048 partials) -------------------
__global__ __launch_bounds__(256) void k_final(const float* __restrict__ lp,
                                               const float* __restrict__ rp,
                                               float* __restrict__ out) {
    __shared__ float red[4];
    int t = threadIdx.x;
    float4 a = ((const float4*)lp)[t];
    float4 b = ((const float4*)lp)[t + 256];
    float4 c = ((const float4*)rp)[t];
    float4 d = ((const float4*)rp)[t + 256];
    float ls = a.x + a.y + a.z + a.w + b.x + b.y + b.z + b.w;
    float rs = c.x + c.y + c.z + c.w + d.x + d.y + d.z + d.w;
    ls = block_reduce(ls, 0, red, t);
    rs = block_reduce(rs, 0, red, t);
    if (t == 0) {
        float lc = ls / (float)BATCH;
        float rg = rs / (float)ALLNUM;
        out[0] = lc + LAM * rg;
        out[1] = lc;
    }
}

extern "C" void kernel_launch(void* const* d_in, const int* in_sizes, int n_in,
                              void* d_out, int out_size, void* d_ws, size_t ws_size,
                              hipStream_t stream) {
    const float* input  = (const float*)d_in[0];
    const int*   target = (const int*)d_in[1];
    const float* P      = (const float*)d_in[2];

    float* ws        = (float*)d_ws;
    float* rnorm     = ws + WS_RNORM;
    float* rowsig    = ws + WS_SIG;
    float* loss_part = ws + WS_LP;
    float* reg_part  = ws + WS_RP;
    unsigned* cnt    = (unsigned*)(ws + WS_CNT);
    ushort_t* Abf    = (ushort_t*)(ws + WS_ABF);
    ushort_t* Pbf    = (ushort_t*)(ws + WS_PBF);
    ushort_t* Stbf   = (ushort_t*)(ws + WS_STBF);
    uint2* list      = (uint2*)(ws + WS_LIST);
    ushort_t* simbf  = (ushort_t*)(ws + WS_SIMBF);
    ushort_t* logits = simbf;            // reuse: sim dead after k_rowloss
    float* out       = (float*)d_out;

    hipLaunchKernelGGL(k_prep1, dim3(32 + 1024 + 4096), dim3(256), 0, stream,
                       P, input, rnorm, rowsig, cnt, Abf, Pbf);
    hipLaunchKernelGGL(k_prep2, dim3((C_CLS / 32) * (DIM / 32)), dim3(256), 0, stream,
                       P, rnorm, Stbf);
    hipLaunchKernelGGL((k_gemm_bt<0>), dim3(ALLNUM / 128, BATCH / 128), dim3(256), 0, stream,
                       Abf, Pbf, rnorm, rowsig, cnt, list, simbf, ALLNUM);
    hipLaunchKernelGGL(k_rowloss, dim3(BATCH), dim3(256), 0, stream,
                       list, cnt, simbf, target, rowsig, loss_part);
    hipLaunchKernelGGL((k_gemm_bt<1>), dim3(C_CLS / 128, ALLNUM / 128), dim3(256), 0, stream,
                       Pbf, Stbf, rnorm, rowsig, cnt, list, logits, C_CLS);
    hipLaunchKernelGGL(k_regloss, dim3(ALLNUM / 4), dim3(256), 0, stream,
                       logits, reg_part);
    hipLaunchKernelGGL(k_final, dim3(1), dim3(256), 0, stream,
                       loss_part, reg_part, out);
}

// Round 9
// 172.174 us; speedup vs baseline: 2.8871x; 2.8871x over previous
//
#include <hip/hip_runtime.h>
#include <hip/hip_bf16.h>
#include <math.h>

#define C_CLS   1024
#define NPROXY  8
#define ALLNUM  8192
#define DIM     512
#define TOPK    410
#define LAM     0.3f
#define BATCH   2048

typedef __bf16 bf16x8 __attribute__((ext_vector_type(8)));
typedef float floatx4 __attribute__((ext_vector_type(4)));
typedef unsigned short ushort_t;

// ws layout (float offsets)
#define WS_RNORM 0                      // 8192
#define WS_SIG   8192                   // 2048 input row norms
#define WS_LP    10240                  // 2048 loss partials
#define WS_RP    12288                  // 2048 reg partials
#define WS_ABF   14336                  // 2048*512 bf16 = 524288 float-slots
#define WS_PBF   538624                 // 8192*512 bf16 = 2097152 float-slots
#define WS_STBF  2635776                // 1024*512 bf16 = 262144 float-slots
#define WS_SIM   2897920                // 2048*8192 fp32; logits bf16 alias after rowloss

// ---------------- helpers ----------------------------------------------------
__device__ inline float block_reduce(float v, int is_max, float* red, int t) {
    #pragma unroll
    for (int o = 32; o > 0; o >>= 1) {
        float w = __shfl_down(v, o);
        v = is_max ? fmaxf(v, w) : (v + w);
    }
    __syncthreads();
    if ((t & 63) == 0) red[t >> 6] = v;
    __syncthreads();
    return is_max ? fmaxf(fmaxf(red[0], red[1]), fmaxf(red[2], red[3]))
                  : (red[0] + red[1] + red[2] + red[3]);
}

__device__ inline ushort_t f2bf(float f) {   // RNE float->bf16
    unsigned u = __float_as_uint(f);
    return (ushort_t)((u + 0x7FFFu + ((u >> 16) & 1u)) >> 16);
}

__device__ inline void ld_g2l_16(const void* g, void* l) {
    __builtin_amdgcn_global_load_lds(
        (const __attribute__((address_space(1))) unsigned int*)g,
        (__attribute__((address_space(3))) unsigned int*)l,
        16, 0, 0);
}

__device__ inline unsigned f2ord(float f) {  // monotone float->uint
    unsigned u = __float_as_uint(f);
    return (u & 0x80000000u) ? ~u : (u | 0x80000000u);
}

// ---------------- K1: fused prep (colnorm | convA+rowsig | tconv P) ----------
__global__ __launch_bounds__(256) void k_prep1(const float* __restrict__ P,
                                               const float* __restrict__ input,
                                               float* __restrict__ rnorm,
                                               float* __restrict__ rowsig,
                                               ushort_t* __restrict__ Abf,
                                               ushort_t* __restrict__ Pbf) {
    __shared__ float tile[32][33];
    __shared__ float red[4];
    int bx = blockIdx.x, t = threadIdx.x;
    if (bx < 32) {
        int j = bx * 256 + t;
        float s = 0.f;
        #pragma unroll 8
        for (int d = 0; d < DIM; ++d) {
            float v = P[(size_t)d * ALLNUM + j];
            s += v * v;
        }
        rnorm[j] = 1.0f / fmaxf(sqrtf(s), 1e-12f);
    } else if (bx < 32 + 1024) {
        // convA: input fp32 -> bf16 + row norms (block covers exactly 2 rows)
        int a = bx - 32;
        int idx = a * 256 + t;
        float4 v = ((const float4*)input)[idx];
        ushort4 o;
        o.x = f2bf(v.x); o.y = f2bf(v.y); o.z = f2bf(v.z); o.w = f2bf(v.w);
        ((ushort4*)Abf)[idx] = o;
        float sq = v.x * v.x + v.y * v.y + v.z * v.z + v.w * v.w;
        #pragma unroll
        for (int off = 32; off > 0; off >>= 1) sq += __shfl_down(sq, off);
        int lane = t & 63, w = t >> 6;
        if (lane == 0) red[w] = sq;
        __syncthreads();
        if (t == 0) {
            rowsig[2 * a]     = sqrtf(red[0] + red[1]);
            rowsig[2 * a + 1] = sqrtf(red[2] + red[3]);
        }
    } else {
        int id = bx - 1056;
        int c0 = (id & 255) * 32, r0 = (id >> 8) * 32;
        int tc = t & 31, tr = t >> 5;
        #pragma unroll
        for (int p = 0; p < 4; ++p)
            tile[tr + p * 8][tc] = P[(size_t)(r0 + tr + p * 8) * ALLNUM + c0 + tc];
        __syncthreads();
        #pragma unroll
        for (int p = 0; p < 4; ++p) {
            int oc = tr + p * 8;
            Pbf[(size_t)(c0 + oc) * DIM + r0 + tc] = f2bf(tile[tc][oc]);
        }
    }
}

// ---------------- K2: S^T bf16 direct: St[c][d] = sum_n P[d][8c+n]*rn[8c+n] --
__global__ __launch_bounds__(256) void k_prep2(const float* __restrict__ P,
                                               const float* __restrict__ rnorm,
                                               ushort_t* __restrict__ Stbf) {
    __shared__ float tile[32][33];       // [d_local][c_local]
    int bx = blockIdx.x, t = threadIdx.x;
    int c0 = (bx & 31) * 32, d0 = (bx >> 5) * 32;
    int cl = t & 31, dl8 = t >> 5;
    #pragma unroll
    for (int p = 0; p < 4; ++p) {
        int d = d0 + dl8 + 8 * p;
        int c = c0 + cl;
        const float* pp = P + (size_t)d * ALLNUM + c * NPROXY;
        const float* rn = rnorm + c * NPROXY;
        float4 a = *(const float4*)pp;
        float4 b = *(const float4*)(pp + 4);
        float4 ra = *(const float4*)rn;
        float4 rb = *(const float4*)(rn + 4);
        tile[dl8 + 8 * p][cl] = a.x * ra.x + a.y * ra.y + a.z * ra.z + a.w * ra.w +
                                b.x * rb.x + b.y * rb.y + b.z * rb.z + b.w * rb.w;
    }
    __syncthreads();
    #pragma unroll
    for (int p = 0; p < 4; ++p) {
        int cl2 = dl8 + 8 * p, dl2 = t & 31;
        Stbf[(size_t)(c0 + cl2) * DIM + d0 + dl2] = f2bf(tile[dl2][cl2]);
    }
}

// ---------------- MFMA GEMM: C[M][N] = A[M][512] * B[N][512]^T ---------------
// MODE 0: C(f32) *= rnorm[col] (sim) ; MODE 1: C(bf16) *= rnorm[row] (logits)
template<int MODE>
__global__ __launch_bounds__(256) void k_gemm_bt(const ushort_t* __restrict__ A,
                                                 const ushort_t* __restrict__ B,
                                                 const float* __restrict__ rnorm,
                                                 void* __restrict__ Cmat, int Ndim) {
    __shared__ __align__(16) ushort_t sA[128 * 64];
    __shared__ __align__(16) ushort_t sB[128 * 64];
    int t = threadIdx.x;
    int w = t >> 6, lane = t & 63;
    int wm = w >> 1, wn = w & 1;
    int bi = blockIdx.y * 128, bj = blockIdx.x * 128;

    floatx4 acc[4][4];
    #pragma unroll
    for (int tm = 0; tm < 4; ++tm)
        #pragma unroll
        for (int tn = 0; tn < 4; ++tn)
            acc[tm][tn] = (floatx4){0.f, 0.f, 0.f, 0.f};

    for (int k0 = 0; k0 < DIM; k0 += 64) {
        #pragma unroll
        for (int it = 0; it < 4; ++it) {
            int c = w * 256 + it * 64 + lane;
            int m = c >> 3, s = c & 7;
            int q = s ^ (m & 7);
            ld_g2l_16(A + ((size_t)(bi + m) << 9) + k0 + q * 8,
                      &sA[(w * 256 + it * 64) * 8]);
        }
        #pragma unroll
        for (int it = 0; it < 4; ++it) {
            int c = w * 256 + it * 64 + lane;
            int m = c >> 3, s = c & 7;
            int q = s ^ (m & 7);
            ld_g2l_16(B + ((size_t)(bj + m) << 9) + k0 + q * 8,
                      &sB[(w * 256 + it * 64) * 8]);
        }
        asm volatile("s_waitcnt vmcnt(0)" ::: "memory");
        __syncthreads();

        #pragma unroll
        for (int kk = 0; kk < 2; ++kk) {
            bf16x8 af[4], bfr[4];
            int ml = lane & 15, q = lane >> 4;
            #pragma unroll
            for (int tm = 0; tm < 4; ++tm) {
                int m = wm * 64 + tm * 16 + ml;
                int s = (kk * 4 + q) ^ (m & 7);
                af[tm] = *(const bf16x8*)&sA[m * 64 + s * 8];
            }
            #pragma unroll
            for (int tn = 0; tn < 4; ++tn) {
                int n = wn * 64 + tn * 16 + ml;
                int s = (kk * 4 + q) ^ (n & 7);
                bfr[tn] = *(const bf16x8*)&sB[n * 64 + s * 8];
            }
            #pragma unroll
            for (int tm = 0; tm < 4; ++tm)
                #pragma unroll
                for (int tn = 0; tn < 4; ++tn)
                    acc[tm][tn] = __builtin_amdgcn_mfma_f32_16x16x32_bf16(
                        af[tm], bfr[tn], acc[tm][tn], 0, 0, 0);
        }
        __syncthreads();
    }

    int ml = lane & 15, qd = lane >> 4;
    #pragma unroll
    for (int tm = 0; tm < 4; ++tm) {
        int rowb = bi + wm * 64 + tm * 16 + qd * 4;
        float4 rnr;
        if (MODE == 1) rnr = *(const float4*)&rnorm[rowb];
        #pragma unroll
        for (int tn = 0; tn < 4; ++tn) {
            int col = bj + wn * 64 + tn * 16 + ml;
            float sc = (MODE == 0) ? rnorm[col] : 0.f;
            #pragma unroll
            for (int i = 0; i < 4; ++i) {
                float v = acc[tm][tn][i] * (MODE == 0 ? sc : ((const float*)&rnr)[i]);
                size_t idx = (size_t)(rowb + i) * Ndim + col;
                if (MODE == 0) ((float*)Cmat)[idx] = v;
                else           ((ushort_t*)Cmat)[idx] = f2bf(v);
            }
        }
    }
}

// ---------------- K4: per-row topk select + class sums + loss ----------------
// Distribution-guided exact select (as R7) with histogram-based band select:
// definite (>=1.80 sig) -> class bins; band [1.47,1.80) -> 256-bin value
// histogram (filled at insert) -> suffix-scan -> exact micro-rank-select in
// the crossing bin (expected ~2-4 members). Fallbacks: O(bc^2) if crossing
// bin > 64 members; full binary search if analytic bounds violated.
#define SEL_CAP 1024
#define GCAP    64

__device__ inline void suffix_select1(unsigned* s_hist, unsigned kk,
                                      unsigned* s_wtot, unsigned* sh_bin,
                                      unsigned* sh_k, int t, int lane, int wid) {
    unsigned h = s_hist[t];
    unsigned v = h;
    #pragma unroll
    for (int off = 1; off < 64; off <<= 1) {
        unsigned o = __shfl_down(v, off);
        if (lane + off < 64) v += o;
    }
    if (lane == 0) s_wtot[wid] = v;
    __syncthreads();
    unsigned above = v - h;
    for (int w2 = wid + 1; w2 < 4; ++w2) above += s_wtot[w2];
    unsigned cum = above + h;
    if (cum >= kk && above < kk) { *sh_bin = (unsigned)t; *sh_k = kk - above; }
    __syncthreads();
}

__global__ __launch_bounds__(256) void k_rowloss(const float* __restrict__ sim,
                                                 const int* __restrict__ target,
                                                 const float* __restrict__ rowsig,
                                                 float* __restrict__ loss_part) {
    __shared__ float    s_cls[C_CLS];        // 4 KB class bins
    __shared__ float    s_bval[SEL_CAP];     // 4 KB band values
    __shared__ ushort_t s_bcol[SEL_CAP];     // 2 KB band cols
    __shared__ unsigned s_bhist[256];        // 1 KB band value histogram
    __shared__ float    s_gval[GCAP];        // crossing-bin members
    __shared__ unsigned s_wtot[4];
    __shared__ unsigned sh_cnt, sh_gc, sh_bin, sh_k;
    __shared__ float    sh_thr;
    __shared__ int      sh_fb;
    __shared__ float    red[4];

    int b = blockIdx.x, t = threadIdx.x;
    int lane = t & 63, wid = t >> 6;
    const float* row = sim + (size_t)b * ALLNUM;
    int tgt = target[b];
    float sig = rowsig[b] * (1.0f / 22.616f);
    float hiT = 1.80f * sig, loT = 1.47f * sig;
    float binscale = 256.0f / (hiT - loT);

    // one global read: cache the row (cols 4f..4f+3 for f = t + 256p)
    float4 v4[8];
    #pragma unroll
    for (int p = 0; p < 8; ++p) v4[p] = ((const float4*)row)[t + 256 * p];

    if (t == 0) { sh_cnt = 0; sh_gc = 0; }
    s_bhist[t] = 0;
    #pragma unroll
    for (int i = 0; i < 4; ++i) s_cls[t + 256 * i] = 0.f;
    __syncthreads();

    // single classify pass from registers
    float ndef = 0.f;
    #pragma unroll
    for (int p = 0; p < 8; ++p) {
        int f = t + 256 * p;
        int cls = f >> 1;                    // class of all 4 elements
        const float* pv = (const float*)&v4[p];
        if (cls == tgt) {
            atomicAdd(&s_cls[tgt], pv[0] + pv[1] + pv[2] + pv[3]);
        } else {
            float ds = 0.f;
            #pragma unroll
            for (int e = 0; e < 4; ++e) {
                float v = pv[e];
                if (v >= hiT) { ds += v; ndef += 1.f; }
                else if (v >= loT) {
                    unsigned idx = atomicAdd(&sh_cnt, 1u);
                    if (idx < SEL_CAP) { s_bval[idx] = v; s_bcol[idx] = (ushort_t)(4 * f + e); }
                    int bin = (int)((v - loT) * binscale);
                    bin = (bin > 255) ? 255 : bin;
                    atomicAdd(&s_bhist[bin], 1u);
                }
            }
            // lanes t and t^1 share cls: pair-combine -> 1 atomic per pair
            float o = __shfl_xor(ds, 1);
            float s2 = ds + o;
            if ((t & 1) == 0 && s2 != 0.f) atomicAdd(&s_cls[cls], s2);
        }
    }
    float ndefT = block_reduce(ndef, 0, red, t);
    int bc = (int)sh_cnt;
    int kq = (TOPK - NPROXY) - (int)ndefT;      // remaining rank among band
    if (t == 0) sh_fb = (kq < 0 || bc < kq || bc > SEL_CAP) ? 1 : 0;
    __syncthreads();

    if (!sh_fb) {
        if (kq > 0) {
            // histogram select: crossing bin + remaining rank
            suffix_select1(s_bhist, (unsigned)kq, s_wtot, &sh_bin, &sh_k, t, lane, wid);
            int B = (int)sh_bin;
            int knew = (int)sh_k;
            // gather crossing-bin members
            for (int j = t; j < bc; j += 256) {
                float v = s_bval[j];
                int bin = (int)((v - loT) * binscale);
                bin = (bin > 255) ? 255 : bin;
                if (bin == B) {
                    unsigned g = atomicAdd(&sh_gc, 1u);
                    if (g < GCAP) s_gval[g] = v;
                }
            }
            __syncthreads();
            int gc = (int)sh_gc;
            if (gc <= GCAP) {
                // micro rank-select: knew-th largest among gc members
                if (t < gc) {
                    float vj = s_gval[t];
                    unsigned g = 0, geq = 0;
                    for (int i = 0; i < gc; ++i) {
                        float vi = s_gval[i];
                        g   += (vi > vj) ? 1u : 0u;
                        geq += (vi >= vj) ? 1u : 0u;
                    }
                    if (g < (unsigned)knew && geq >= (unsigned)knew) sh_thr = vj;
                }
            } else {
                // medium fallback: O(bc^2) rank-select over the whole band
                for (int j = t; j < bc; j += 256) {
                    float vj = s_bval[j];
                    unsigned g = 0, geq = 0;
                    for (int i = 0; i < bc; ++i) {
                        float vi = s_bval[i];
                        g   += (vi > vj) ? 1u : 0u;
                        geq += (vi >= vj) ? 1u : 0u;
                    }
                    if (g < (unsigned)kq && geq >= (unsigned)kq) sh_thr = vj;
                }
            }
            __syncthreads();
            float thr = sh_thr;
            for (int j = t; j < bc; j += 256)
                if (s_bval[j] >= thr)
                    atomicAdd(&s_cls[s_bcol[j] >> 3], s_bval[j]);
        }
    } else {
        // exact fallback: rebuild bins via binary search on ord
        __syncthreads();
        #pragma unroll
        for (int i = 0; i < 4; ++i) s_cls[t + 256 * i] = 0.f;
        __syncthreads();
        #pragma unroll
        for (int p = 0; p < 8; ++p) {
            int f = t + 256 * p;
            const float* pv = (const float*)&v4[p];
            if ((f >> 1) == tgt)
                atomicAdd(&s_cls[tgt], pv[0] + pv[1] + pv[2] + pv[3]);
        }
        unsigned L = 0u, R = 0xFFFFFFFFu;
        for (int it = 0; it < 33 && R - L > 1; ++it) {
            unsigned mid = L + ((R - L) >> 1);
            float c = 0.f;
            #pragma unroll
            for (int p = 0; p < 8; ++p) {
                int f = t + 256 * p;
                const float* pv = (const float*)&v4[p];
                if ((f >> 1) != tgt) {
                    #pragma unroll
                    for (int e = 0; e < 4; ++e)
                        c += (f2ord(pv[e]) >= mid) ? 1.f : 0.f;
                }
            }
            c = block_reduce(c, 0, red, t);
            if (c >= (float)(TOPK - NPROXY)) L = mid; else R = mid;
            __syncthreads();
        }
        #pragma unroll
        for (int p = 0; p < 8; ++p) {
            int f = t + 256 * p;
            const float* pv = (const float*)&v4[p];
            if ((f >> 1) != tgt) {
                #pragma unroll
                for (int e = 0; e < 4; ++e)
                    if (f2ord(pv[e]) >= L)
                        atomicAdd(&s_cls[f >> 1], pv[e]);
            }
        }
    }
    __syncthreads();

    // masked (logit != 0) stable softmax loss — one float4 per thread
    float4 cv = ((const float4*)s_cls)[t];
    float m = -1e30f;
    if (cv.x != 0.0f) m = fmaxf(m, cv.x);
    if (cv.y != 0.0f) m = fmaxf(m, cv.y);
    if (cv.z != 0.0f) m = fmaxf(m, cv.z);
    if (cv.w != 0.0f) m = fmaxf(m, cv.w);
    m = block_reduce(m, 1, red, t);
    float se = 0.f;
    if (cv.x != 0.0f) se += expf(cv.x - m);
    if (cv.y != 0.0f) se += expf(cv.y - m);
    if (cv.z != 0.0f) se += expf(cv.z - m);
    if (cv.w != 0.0f) se += expf(cv.w - m);
    se = block_reduce(se, 0, red, t);
    if (t == 0) {
        float lt = s_cls[tgt];
        float predict_t = expf(lt - m) / (1e-8f * expf(-m) + se);
        loss_part[b] = -logf(predict_t + 1e-20f);
    }
}

// ---------------- K5: reg logsumexp - diag, one wave per row (bf16 in) -------
__global__ __launch_bounds__(256) void k_regloss(const ushort_t* __restrict__ logits,
                                                 float* __restrict__ reg_part) {
    __shared__ float bsum[4];
    int t = threadIdx.x, lane = t & 63, wid = t >> 6;
    int i = blockIdx.x * 4 + wid;
    const ushort_t* row = logits + (size_t)i * C_CLS;
    uint4 c0 = ((const uint4*)row)[lane];
    uint4 c1 = ((const uint4*)(row + 512))[lane];

    float f[16];
    const unsigned* u0 = (const unsigned*)&c0;
    const unsigned* u1 = (const unsigned*)&c1;
    #pragma unroll
    for (int k = 0; k < 4; ++k) {
        f[2 * k]     = __uint_as_float(u0[k] << 16);
        f[2 * k + 1] = __uint_as_float(u0[k] & 0xFFFF0000u);
        f[8 + 2 * k]     = __uint_as_float(u1[k] << 16);
        f[8 + 2 * k + 1] = __uint_as_float(u1[k] & 0xFFFF0000u);
    }

    int cstar = i >> 3;
    int chunk = cstar >> 9, within = cstar & 511;
    float sd = 0.f;
    if (lane == (within >> 3)) sd = f[chunk * 8 + (within & 7)];

    float m = -1e30f;
    #pragma unroll
    for (int k = 0; k < 16; ++k) m = fmaxf(m, f[k]);
    #pragma unroll
    for (int off = 32; off > 0; off >>= 1) m = fmaxf(m, __shfl_xor(m, off));

    float se = 0.f;
    #pragma unroll
    for (int k = 0; k < 16; ++k) se += expf(f[k] - m);
    #pragma unroll
    for (int off = 32; off > 0; off >>= 1) se += __shfl_xor(se, off);
    #pragma unroll
    for (int off = 32; off > 0; off >>= 1) sd += __shfl_xor(sd, off);

    if (lane == 0) bsum[wid] = m + logf(se) - sd;
    __syncthreads();
    if (t == 0)
        reg_part[blockIdx.x] = bsum[0] + bsum[1] + bsum[2] + bsum[3];
}

// ---------------- K6: finalize (reduce 2048+2048 partials) -------------------
__global__ __launch_bounds__(256) void k_final(const float* __restrict__ lp,
                                               const float* __restrict__ rp,
                                               float* __restrict__ out) {
    __shared__ float red[4];
    int t = threadIdx.x;
    float4 a = ((const float4*)lp)[t];
    float4 b = ((const float4*)lp)[t + 256];
    float4 c = ((const float4*)rp)[t];
    float4 d = ((const float4*)rp)[t + 256];
    float ls = a.x + a.y + a.z + a.w + b.x + b.y + b.z + b.w;
    float rs = c.x + c.y + c.z + c.w + d.x + d.y + d.z + d.w;
    ls = block_reduce(ls, 0, red, t);
    rs = block_reduce(rs, 0, red, t);
    if (t == 0) {
        float lc = ls / (float)BATCH;
        float rg = rs / (float)ALLNUM;
        out[0] = lc + LAM * rg;
        out[1] = lc;
    }
}

extern "C" void kernel_launch(void* const* d_in, const int* in_sizes, int n_in,
                              void* d_out, int out_size, void* d_ws, size_t ws_size,
                              hipStream_t stream) {
    const float* input  = (const float*)d_in[0];
    const int*   target = (const int*)d_in[1];
    const float* P      = (const float*)d_in[2];

    float* ws       = (float*)d_ws;
    float* rnorm    = ws + WS_RNORM;
    float* rowsig   = ws + WS_SIG;
    float* loss_part= ws + WS_LP;
    float* reg_part = ws + WS_RP;
    ushort_t* Abf   = (ushort_t*)(ws + WS_ABF);
    ushort_t* Pbf   = (ushort_t*)(ws + WS_PBF);
    ushort_t* Stbf  = (ushort_t*)(ws + WS_STBF);
    float* sim      = ws + WS_SIM;
    ushort_t* logits= (ushort_t*)sim;   // reuse: sim dead after k_rowloss
    float* out      = (float*)d_out;

    hipLaunchKernelGGL(k_prep1, dim3(32 + 1024 + 4096), dim3(256), 0, stream,
                       P, input, rnorm, rowsig, Abf, Pbf);
    hipLaunchKernelGGL(k_prep2, dim3((C_CLS / 32) * (DIM / 32)), dim3(256), 0, stream,
                       P, rnorm, Stbf);
    hipLaunchKernelGGL((k_gemm_bt<0>), dim3(ALLNUM / 128, BATCH / 128), dim3(256), 0, stream,
                       Abf, Pbf, rnorm, sim, ALLNUM);
    hipLaunchKernelGGL(k_rowloss, dim3(BATCH), dim3(256), 0, stream,
                       sim, target, rowsig, loss_part);
    hipLaunchKernelGGL((k_gemm_bt<1>), dim3(C_CLS / 128, ALLNUM / 128), dim3(256), 0, stream,
                       Pbf, Stbf, rnorm, logits, C_CLS);
    hipLaunchKernelGGL(k_regloss, dim3(ALLNUM / 4), dim3(256), 0, stream,
                       logits, reg_part);
    hipLaunchKernelGGL(k_final, dim3(1), dim3(256), 0, stream,
                       loss_part, reg_part, out);
}